// Round 4
// baseline (7076276.562 us; speedup 1.0000x reference)
//
#include <hip/hip_runtime.h>

// Seq2SeqWithAlignment: enc/dec LSTM -> hpre -> logits logsumexp -> Viterbi align.
// K=64 enc steps, T=128 dec tokens (127 dec steps used), H=512, E=100, V=32000.

#define K_ENC 64
#define HID   512
#define EMB   100
#define VOC   32000
#define G4    2048   // 4*HID

typedef __attribute__((ext_vector_type(8))) short  short8;
typedef __attribute__((ext_vector_type(4))) float  f32x4;

#define LOG2E 1.4426950408889634f
#define LN2   0.6931471805599453f

__device__ __forceinline__ unsigned short f2bf(float f) {
  union { float f; unsigned u; } x; x.f = f;
  unsigned r = x.u + 0x7FFFu + ((x.u >> 16) & 1u);  // RNE
  return (unsigned short)(r >> 16);
}

__device__ __forceinline__ float fast_sigmoid(float x) {
  // 1/(1+2^(-x*log2e)); saturates cleanly (rcp(inf)=0)
  return __builtin_amdgcn_rcpf(1.f + __builtin_amdgcn_exp2f(-LOG2E * x));
}
__device__ __forceinline__ float fast_tanh(float x) {
  // 1 - 2/(2^(2x*log2e)+1); x->+inf: 1, x->-inf: -1
  return 1.f - 2.f * __builtin_amdgcn_rcpf(1.f + __builtin_amdgcn_exp2f(2.f * LOG2E * x));
}

// ---------------- workspace layout (float offsets) ----------------
#define OFF_PAD   0         // 256 floats: unused
#define OFF_HBUF  256       // 4096 floats = 2048 u64: tagged h channels [grp][slot][512]
#define OFF_G0E   4352      // 64*2048  : enc Wih@x + bih + bhh
#define OFF_G0D   135424    // 127*2048 : dec
#define OFF_EENC  395520    // 64*512
#define OFF_D     428288    // 127*512
#define OFF_EWE   493312    // 64*100   : log2e * Eenc@We_E^T
#define OFF_DWD   499712    // 127*100  : log2e * (D@We_D^T + beh)
#define OFF_BEM   512412    // 32000    : log2e * bem
#define OFF_SUM   544412    // 127*64   : sum of 2^s over v (atomic)
#define OFF_EM    552540    // 127*64   : emission
#define OFF_WEM   560668    // ushort[4096000]: Wem bf16 in MFMA-B fragment-linear layout
// total ~10.4 MB

// ---------------- zero init (tagged h channels => tag 0 / value 0, sumexp) ----------------
__global__ void kZero(float* ws) {
  int gid = blockIdx.x * 256 + threadIdx.x;
  if (gid < 4352) ws[gid] = 0.f;
  else if (gid < 4352 + 127 * 64) ws[OFF_SUM + gid - 4352] = 0.f;
}

// ---------------- G0 = Wih @ emb[tok] + bih + bhh ----------------
__global__ __launch_bounds__(256) void kG0(const int* x, const int* y, const float* emb,
                    const float* eWih, const float* ebih, const float* ebhh,
                    const float* dWih, const float* dbih, const float* dbhh,
                    float* ws) {
  int gid = blockIdx.x * 256 + threadIdx.x;
  const int enc_total = K_ENC * G4;
  if (gid >= enc_total + 127 * G4) return;
  bool enc = gid < enc_total;
  int loc = enc ? gid : gid - enc_total;
  int t = loc >> 11, r = loc & (G4 - 1);
  int tok = enc ? x[t] : y[t];
  const float* Wr = (enc ? eWih : dWih) + r * EMB;
  const float* er = emb + tok * EMB;
  float s = 0.f;
  #pragma unroll 4
  for (int e = 0; e < EMB; ++e) s += er[e] * Wr[e];
  s += enc ? (ebih[r] + ebhh[r]) : (dbih[r] + dbhh[r]);
  ws[(enc ? OFF_G0E : OFF_G0D) + t * G4 + r] = s;
}

// ---------------- Wem -> bf16 MFMA-B fragment-linear layout, bem scaled ----------------
// block (vt,kb) = 1KB: lane L holds Wem[vt*16+(L&15)][kb*32+(L>>4)*8+j], j=0..7 (0-pad k>=100)
__global__ __launch_bounds__(256) void kWemPrep(const float* Wem, const float* bem, float* ws) {
  int gid = blockIdx.x * 256 + threadIdx.x;   // < 4096000
  int vt = gid >> 11;
  int kb = (gid >> 9) & 3;
  int L  = (gid >> 3) & 63;
  int j  = gid & 7;
  int v = vt * 16 + (L & 15);
  int k = kb * 32 + ((L >> 4) << 3) + j;
  float val = (k < EMB) ? Wem[v * EMB + k] : 0.f;
  ((unsigned short*)(ws + OFF_WEM))[gid] = f2bf(val);
  if (gid < VOC) ws[OFF_BEM + gid] = bem[gid] * LOG2E;
}

// ---------------- persistent LSTM: 64 WGs (32 enc + 32 dec), weights in VGPRs ----------------
// Sync via tagged 64-bit relaxed atomics: word = (tag<<32)|f32bits. No barriers, no fences.
// Safety: writing tag t+1 requires observing all 512 tag-t words, which implies every wave
// finished reading t-1 -> the slot being overwritten ((t+1)&1) is dead. Double-buffer OK.
// Poll is BOUNDED (16384 iters): converts any sync failure into a finite wrong-answer run
// instead of a harness-timeout hang. Cap is never reached in normal operation.
__global__ __launch_bounds__(512) void kLstm(const float* eWhh, const float* dWhh, float* ws) {
  const int grp = blockIdx.x >> 5;            // 0=enc, 1=dec
  const int wg  = blockIdx.x & 31;
  const float* Whh = grp ? dWhh : eWhh;
  const float* G0  = ws + (grp ? OFF_G0D : OFF_G0E);
  float* hs = ws + (grp ? OFF_D : OFF_EENC);
  unsigned long long* hb = (unsigned long long*)(ws + OFF_HBUF) + grp * 1024;  // [2][512]
  const int steps = grp ? 127 : K_ENC;
  const int tid = threadIdx.x;
  const int jl = tid >> 5, sub = tid & 31;
  const int j = wg * 16 + jl;                 // owned h index
  // per-thread weight slice: 4 gates x 16 k  (rows g*512+j, cols sub*16..+16) = 64 VGPRs
  float4 w4[16];
  #pragma unroll
  for (int g = 0; g < 4; ++g)
    #pragma unroll
    for (int q = 0; q < 4; ++q)
      w4[g * 4 + q] = *(const float4*)&Whh[(g * HID + j) * HID + sub * 16 + q * 4];
  float cst = 0.f;
  for (int t = 0; t < steps; ++t) {
    float g0i = G0[t * G4 + j];
    float g0f = G0[t * G4 + HID + j];
    float g0g = G0[t * G4 + 2 * HID + j];
    float g0o = G0[t * G4 + 3 * HID + j];
    unsigned long long* hsrc = hb + (t & 1) * 512 + sub * 16;
    const unsigned tag = (unsigned)t;
    unsigned long long v[16];
    bool ok;
    int guard = 0;
    do {                                      // batched poll: 16 loads in flight, then check
      ok = true;
      #pragma unroll
      for (int kk = 0; kk < 16; ++kk)
        v[kk] = __hip_atomic_load(hsrc + kk, __ATOMIC_RELAXED, __HIP_MEMORY_SCOPE_AGENT);
      #pragma unroll
      for (int kk = 0; kk < 16; ++kk)
        ok = ok && ((unsigned)(v[kk] >> 32) == tag);
    } while (!ok && (++guard < 16384));
    float h[16];
    #pragma unroll
    for (int kk = 0; kk < 16; ++kk) {
      union { unsigned u; float f; } c; c.u = (unsigned)v[kk]; h[kk] = c.f;
    }
    float p0 = 0.f, p1 = 0.f, p2 = 0.f, p3 = 0.f;
    #pragma unroll
    for (int q = 0; q < 4; ++q) {
      p0 += w4[0+q].x*h[q*4+0] + w4[0+q].y*h[q*4+1] + w4[0+q].z*h[q*4+2] + w4[0+q].w*h[q*4+3];
      p1 += w4[4+q].x*h[q*4+0] + w4[4+q].y*h[q*4+1] + w4[4+q].z*h[q*4+2] + w4[4+q].w*h[q*4+3];
      p2 += w4[8+q].x*h[q*4+0] + w4[8+q].y*h[q*4+1] + w4[8+q].z*h[q*4+2] + w4[8+q].w*h[q*4+3];
      p3 += w4[12+q].x*h[q*4+0] + w4[12+q].y*h[q*4+1] + w4[12+q].z*h[q*4+2] + w4[12+q].w*h[q*4+3];
    }
    #pragma unroll
    for (int d = 1; d <= 16; d <<= 1) {       // reduce over 32 sub-lanes (stays in 32-half)
      p0 += __shfl_xor(p0, d); p1 += __shfl_xor(p1, d);
      p2 += __shfl_xor(p2, d); p3 += __shfl_xor(p3, d);
    }
    float si = fast_sigmoid(g0i + p0);
    float sf = fast_sigmoid(g0f + p1);
    float gG = fast_tanh(g0g + p2);
    float so = fast_sigmoid(g0o + p3);
    cst = sf * cst + si * gG;
    float hn = so * fast_tanh(cst);
    if (sub == 0) {
      union { float f; unsigned u; } hu; hu.f = hn;
      unsigned long long pack = ((unsigned long long)(tag + 1u) << 32) | (unsigned long long)hu.u;
      __hip_atomic_store(&hb[((t + 1) & 1) * 512 + j], pack, __ATOMIC_RELAXED, __HIP_MEMORY_SCOPE_AGENT);
      hs[t * HID + j] = hn;
    }
  }
}

// ---------------- EWe_s / DWd_s projections (scaled by log2e) ----------------
__global__ __launch_bounds__(256) void kProj(const float* Weh, const float* beh, float* ws) {
  int bid = blockIdx.x;                 // 0..190
  bool enc = bid < K_ENC;
  int row = enc ? bid : bid - K_ENC;
  const float* in = ws + (enc ? OFF_EENC : OFF_D) + row * HID;
  __shared__ float sin_[HID];
  int tid = threadIdx.x;
  sin_[tid] = in[tid]; sin_[tid + 256] = in[tid + 256];
  __syncthreads();
  if (tid < EMB) {
    const float* wr = Weh + tid * 1024 + (enc ? 0 : HID);
    float s = 0.f;
    #pragma unroll 4
    for (int h = 0; h < HID; ++h) s += sin_[h] * wr[h];
    if (!enc) s += beh[tid];
    ws[(enc ? OFF_EWE : OFF_DWD) + row * EMB + tid] = s * LOG2E;
  }
}

// ---------------- fused logits GEMM (bf16 MFMA) + online sum(2^s) ----------------
__global__ __launch_bounds__(256) void kLogits(float* ws) {
  const int t = blockIdx.x >> 2;
  const int chunk = blockIdx.x & 3;
  const int tid = threadIdx.x;
  const int lane = tid & 63;
  const int wv = tid >> 6;
  const int quad = lane >> 4, l15 = lane & 15;
  __shared__ __align__(16) unsigned short A[64 * 128];   // hpre_s bf16, [m][k] k-padded to 128
  const float* EWe = ws + OFF_EWE;
  const float* DWd = ws + OFF_DWD + t * EMB;
  for (int idx = tid; idx < 64 * 128; idx += 256) {
    int m = idx >> 7, k = idx & 127;
    float hv = 0.f;
    if (k < EMB) { float s = EWe[m * EMB + k] + DWd[k]; hv = s > 0.f ? s : 0.f; }
    A[idx] = f2bf(hv);
  }
  __syncthreads();
  short8 af[4][4];   // A fragments persistent in VGPRs: [mtile][kblock]
  #pragma unroll
  for (int mt = 0; mt < 4; ++mt)
    #pragma unroll
    for (int kb = 0; kb < 4; ++kb)
      af[mt][kb] = *(const short8*)&A[(mt * 16 + l15) * 128 + kb * 32 + quad * 8];
  const unsigned short* wem = (const unsigned short*)(ws + OFF_WEM);
  const float* bem_s = ws + OFF_BEM;
  float rs[4][4];
  #pragma unroll
  for (int a = 0; a < 4; ++a)
    #pragma unroll
    for (int b = 0; b < 4; ++b) rs[a][b] = 0.f;
  int vt = chunk * 500 + wv;
  short8 nb0, nb1, nb2, nb3; float nbi;
  nb0 = *(const short8*)&wem[(vt * 4 + 0) * 512 + lane * 8];
  nb1 = *(const short8*)&wem[(vt * 4 + 1) * 512 + lane * 8];
  nb2 = *(const short8*)&wem[(vt * 4 + 2) * 512 + lane * 8];
  nb3 = *(const short8*)&wem[(vt * 4 + 3) * 512 + lane * 8];
  nbi = bem_s[vt * 16 + l15];
  for (int ii = wv; ii < 500; ii += 4) {
    short8 cb0 = nb0, cb1 = nb1, cb2 = nb2, cb3 = nb3;
    float cbi = nbi;
    int nvt = vt + 4;
    if (ii + 4 < 500) {   // software pipeline next B tile
      nb0 = *(const short8*)&wem[(nvt * 4 + 0) * 512 + lane * 8];
      nb1 = *(const short8*)&wem[(nvt * 4 + 1) * 512 + lane * 8];
      nb2 = *(const short8*)&wem[(nvt * 4 + 2) * 512 + lane * 8];
      nb3 = *(const short8*)&wem[(nvt * 4 + 3) * 512 + lane * 8];
      nbi = bem_s[nvt * 16 + l15];
    }
    f32x4 acc[4];
    #pragma unroll
    for (int mt = 0; mt < 4; ++mt) acc[mt] = (f32x4){cbi, cbi, cbi, cbi};  // init with bem
    #pragma unroll
    for (int mt = 0; mt < 4; ++mt) {
      acc[mt] = __builtin_amdgcn_mfma_f32_16x16x32_bf16(af[mt][0], cb0, acc[mt], 0, 0, 0);
      acc[mt] = __builtin_amdgcn_mfma_f32_16x16x32_bf16(af[mt][1], cb1, acc[mt], 0, 0, 0);
      acc[mt] = __builtin_amdgcn_mfma_f32_16x16x32_bf16(af[mt][2], cb2, acc[mt], 0, 0, 0);
      acc[mt] = __builtin_amdgcn_mfma_f32_16x16x32_bf16(af[mt][3], cb3, acc[mt], 0, 0, 0);
    }
    #pragma unroll
    for (int mt = 0; mt < 4; ++mt)
      #pragma unroll
      for (int r = 0; r < 4; ++r)
        rs[mt][r] += __builtin_amdgcn_exp2f(acc[mt][r]);   // s already includes log2e scale
    vt = nvt;
  }
  // reduce across the 16 column-lanes of each quad, then one atomic per row
  #pragma unroll
  for (int d = 1; d < 16; d <<= 1)
    #pragma unroll
    for (int mt = 0; mt < 4; ++mt)
      #pragma unroll
      for (int r = 0; r < 4; ++r)
        rs[mt][r] += __shfl_xor(rs[mt][r], d);
  if (l15 == 0) {
    float* sum = ws + OFF_SUM + t * 64;
    #pragma unroll
    for (int mt = 0; mt < 4; ++mt)
      #pragma unroll
      for (int r = 0; r < 4; ++r)
        atomicAdd(&sum[mt * 16 + quad * 4 + r], rs[mt][r]);
  }
}

// ---------------- emission = ln2 * (s_word - log2(sum 2^s)), s_word in fp32 ----------------
__global__ __launch_bounds__(256) void kEmission(const int* y, const float* Wem, float* ws) {
  int gid = blockIdx.x * 256 + threadIdx.x;
  if (gid >= 127 * 64) return;
  int t = gid >> 6, m = gid & 63;
  const float* ew = ws + OFF_EWE + m * EMB;
  const float* dw = ws + OFF_DWD + t * EMB;
  int wt = y[t + 1];
  const float* wr = Wem + wt * EMB;
  float s = ws[OFF_BEM + wt];
  #pragma unroll 4
  for (int e = 0; e < EMB; ++e) {
    float h = ew[e] + dw[e];
    h = h > 0.f ? h : 0.f;
    s += h * wr[e];
  }
  ws[OFF_EM + gid] = LN2 * (s - __builtin_amdgcn_logf(ws[OFF_SUM + gid]));
}

// ---------------- Viterbi: prefix-max trick + backtrace ----------------
// tranm[i][j] = fe + fs*(63-i-j) (i+j<64). scores[i][j] = q[i] + fe + fs*(63-j), q[i]=pa[i]-fs*i.
// flip cancels: new_pa[j] = P[j] + fe + fs*j + em[t][j]; ind'[j] = argP[j]  (P = prefix max of q).
__global__ __launch_bounds__(256) void kViterbi(const float* ws, float* out) {
  __shared__ float em_lds[127 * 64];
  __shared__ int   inds[128 * 64];
  __shared__ float sval;
  const int tid = threadIdx.x;
  for (int i = tid; i < 127 * 64; i += 256) em_lds[i] = ws[OFF_EM + i];
  if (tid < 64) inds[tid] = 0;   // indices row 0
  __syncthreads();
  if (tid < 64) {
    const int j = tid;
    const float fs = -0.4054651081081644f;   // log(128/192)
    const float fe = -1.0986122886681098f;   // log(64/192)
    float pa = 0.f;
    float emnext = em_lds[j];
    for (int t = 0; t < 127; ++t) {
      float emc = emnext;
      if (t < 126) emnext = em_lds[(t + 1) * 64 + j];
      float v = fmaf(-fs, (float)j, pa);   // q[j]
      int idx = j;
      #pragma unroll
      for (int d = 1; d < 64; d <<= 1) {   // inclusive prefix max, earliest argmax on ties
        float vv = __shfl_up(v, d);
        int   ii = __shfl_up(idx, d);
        bool cur = v > vv;                 // strict >: keep earlier index on ties
        v   = cur ? v : vv;
        idx = cur ? idx : ii;
      }
      pa = v + fe + fs * (float)j + emc;
      inds[(t + 1) * 64 + j] = idx;
    }
    if (j == 63) sval = pa;
  }
  __syncthreads();
  if (tid == 0) {
    int ind = 63;
    for (int t = 127; t >= 0; --t) {
      ind = inds[t * 64 + ind];
      out[t] = (float)ind;
    }
    out[128] = sval;
  }
}

extern "C" void kernel_launch(void* const* d_in, const int* in_sizes, int n_in,
                              void* d_out, int out_size, void* d_ws, size_t ws_size,
                              hipStream_t stream) {
  const int*   x    = (const int*)d_in[0];
  const int*   y    = (const int*)d_in[1];
  const float* emb  = (const float*)d_in[2];
  const float* eWih = (const float*)d_in[3];
  const float* eWhh = (const float*)d_in[4];
  const float* ebih = (const float*)d_in[5];
  const float* ebhh = (const float*)d_in[6];
  const float* dWih = (const float*)d_in[7];
  const float* dWhh = (const float*)d_in[8];
  const float* dbih = (const float*)d_in[9];
  const float* dbhh = (const float*)d_in[10];
  const float* Weh  = (const float*)d_in[11];
  const float* beh  = (const float*)d_in[12];
  const float* Wem  = (const float*)d_in[13];
  const float* bem  = (const float*)d_in[14];
  float* ws  = (float*)d_ws;
  float* out = (float*)d_out;

  hipLaunchKernelGGL(kZero,     dim3(49),    dim3(256), 0, stream, ws);
  hipLaunchKernelGGL(kG0,       dim3(1528),  dim3(256), 0, stream, x, y, emb, eWih, ebih, ebhh, dWih, dbih, dbhh, ws);
  hipLaunchKernelGGL(kWemPrep,  dim3(16000), dim3(256), 0, stream, Wem, bem, ws);
  hipLaunchKernelGGL(kLstm,     dim3(64),    dim3(512), 0, stream, eWhh, dWhh, ws);
  hipLaunchKernelGGL(kProj,     dim3(191),   dim3(256), 0, stream, Weh, beh, ws);
  hipLaunchKernelGGL(kLogits,   dim3(508),   dim3(256), 0, stream, ws);
  hipLaunchKernelGGL(kEmission, dim3(32),    dim3(256), 0, stream, y, Wem, ws);
  hipLaunchKernelGGL(kViterbi,  dim3(1),     dim3(256), 0, stream, ws, out);
}

// Round 5
// 668.164 us; speedup vs baseline: 10590.6352x; 10590.6352x over previous
//
#include <hip/hip_runtime.h>

// Seq2SeqWithAlignment: enc/dec LSTM -> hpre -> logits logsumexp -> Viterbi align.
// K=64 enc steps, T=128 dec tokens (127 dec steps used), H=512, E=100, V=32000.

#define K_ENC 64
#define HID   512
#define EMB   100
#define VOC   32000
#define G4    2048   // 4*HID

typedef __attribute__((ext_vector_type(8))) short  short8;
typedef __attribute__((ext_vector_type(4))) float  f32x4;

#define LOG2E 1.4426950408889634f
#define LN2   0.6931471805599453f

__device__ __forceinline__ unsigned short f2bf(float f) {
  union { float f; unsigned u; } x; x.f = f;
  unsigned r = x.u + 0x7FFFu + ((x.u >> 16) & 1u);  // RNE
  return (unsigned short)(r >> 16);
}

__device__ __forceinline__ float fast_sigmoid(float x) {
  return __builtin_amdgcn_rcpf(1.f + __builtin_amdgcn_exp2f(-LOG2E * x));
}
__device__ __forceinline__ float fast_tanh(float x) {
  return 1.f - 2.f * __builtin_amdgcn_rcpf(1.f + __builtin_amdgcn_exp2f(2.f * LOG2E * x));
}

// ---------------- workspace layout (float offsets) ----------------
#define OFF_PAD   0         // 256 floats: unused
#define OFF_HBUF  256       // 4096 floats = 2048 u64: tagged h channels [grp][slot][512]
#define OFF_G0E   4352      // 64*2048  : enc Wih@x + bih + bhh
#define OFF_G0D   135424    // 127*2048 : dec
#define OFF_EENC  395520    // 64*512
#define OFF_D     428288    // 127*512
#define OFF_EWE   493312    // 64*100   : log2e * Eenc@We_E^T
#define OFF_DWD   499712    // 127*100  : log2e * (D@We_D^T + beh)
#define OFF_BEM   512412    // 32000    : log2e * bem
#define OFF_SUM   544412    // 127*64   : sum of 2^s over v (atomic)
#define OFF_EM    552540    // 127*64   : emission
#define OFF_WEM   560668    // ushort[4096000]: Wem bf16 in MFMA-B fragment-linear layout
// total ~10.4 MB

// ---------------- zero init (tagged h channels => tag 0 / value 0, sumexp) ----------------
__global__ void kZero(float* ws) {
  int gid = blockIdx.x * 256 + threadIdx.x;
  if (gid < 4352) ws[gid] = 0.f;
  else if (gid < 4352 + 127 * 64) ws[OFF_SUM + gid - 4352] = 0.f;
}

// ---------------- G0 = Wih @ emb[tok] + bih + bhh ----------------
__global__ __launch_bounds__(256) void kG0(const int* x, const int* y, const float* emb,
                    const float* eWih, const float* ebih, const float* ebhh,
                    const float* dWih, const float* dbih, const float* dbhh,
                    float* ws) {
  int gid = blockIdx.x * 256 + threadIdx.x;
  const int enc_total = K_ENC * G4;
  if (gid >= enc_total + 127 * G4) return;
  bool enc = gid < enc_total;
  int loc = enc ? gid : gid - enc_total;
  int t = loc >> 11, r = loc & (G4 - 1);
  int tok = enc ? x[t] : y[t];
  const float* Wr = (enc ? eWih : dWih) + r * EMB;
  const float* er = emb + tok * EMB;
  float s = 0.f;
  #pragma unroll 4
  for (int e = 0; e < EMB; ++e) s += er[e] * Wr[e];
  s += enc ? (ebih[r] + ebhh[r]) : (dbih[r] + dbhh[r]);
  ws[(enc ? OFF_G0E : OFF_G0D) + t * G4 + r] = s;
}

// ---------------- Wem -> bf16 MFMA-B fragment-linear layout, bem scaled ----------------
// block (vt,kb) = 1KB: lane L holds Wem[vt*16+(L&15)][kb*32+(L>>4)*8+j], j=0..7 (0-pad k>=100)
__global__ __launch_bounds__(256) void kWemPrep(const float* Wem, const float* bem, float* ws) {
  int gid = blockIdx.x * 256 + threadIdx.x;   // < 4096000
  int vt = gid >> 11;
  int kb = (gid >> 9) & 3;
  int L  = (gid >> 3) & 63;
  int j  = gid & 7;
  int v = vt * 16 + (L & 15);
  int k = kb * 32 + ((L >> 4) << 3) + j;
  float val = (k < EMB) ? Wem[v * EMB + k] : 0.f;
  ((unsigned short*)(ws + OFF_WEM))[gid] = f2bf(val);
  if (gid < VOC) ws[OFF_BEM + gid] = bem[gid] * LOG2E;
}

// ---------------- persistent LSTM: 64 WGs (32 enc + 32 dec), weights in VGPRs ----------------
// Sync via tagged 64-bit words (tag<<32 | f32bits) moved with atomic RMWs ONLY:
//   producer: atomicExch (executes at coherence point -> promptly visible to all XCDs)
//   consumer: wave 0 polls with atomicOr(ptr,0) (coherence-point read), s_sleep backoff,
//             deposits h into LDS; one __syncthreads; all 8 waves read from LDS.
// R4 lesson: relaxed agent-scope load/store polled stale per-XCD L2 lines -> 37ms/step.
// RMWs are the measured-correct prompt path (kLogits' cross-XCD atomicAdd).
// Single barrier/step is safe: poll(t+1) success implies this WG's own waves published t+1,
// which implies they already read h_lds for step t -> wave0 may overwrite h_lds.
// Poll is BOUNDED: sync failure => finite wrong answer, not a harness-timeout hang.
__global__ __launch_bounds__(512) void kLstm(const float* eWhh, const float* dWhh, float* ws) {
  const int grp = blockIdx.x >> 5;            // 0=enc, 1=dec
  const int wg  = blockIdx.x & 31;
  const float* Whh = grp ? dWhh : eWhh;
  const float* G0  = ws + (grp ? OFF_G0D : OFF_G0E);
  float* hs = ws + (grp ? OFF_D : OFF_EENC);
  unsigned long long* hb = (unsigned long long*)(ws + OFF_HBUF) + grp * 1024;  // [2][512]
  const int steps = grp ? 127 : K_ENC;
  const int tid = threadIdx.x;
  const int jl = tid >> 5, sub = tid & 31;
  const int j = wg * 16 + jl;                 // owned h index
  __shared__ float h_lds[32 * 20];            // [sub][16] padded to 20 (bank spread)
  // per-thread weight slice: 4 gates x 16 k  (rows g*512+j, cols sub*16..+16) = 64 VGPRs
  float4 w4[16];
  #pragma unroll
  for (int g = 0; g < 4; ++g)
    #pragma unroll
    for (int q = 0; q < 4; ++q)
      w4[g * 4 + q] = *(const float4*)&Whh[(g * HID + j) * HID + sub * 16 + q * 4];
  float cst = 0.f;
  for (int t = 0; t < steps; ++t) {
    // ---- wave 0: coherence-point poll of all 512 words (8 per lane) ----
    if (tid < 64) {
      unsigned long long* src = hb + (t & 1) * 512 + tid * 8;
      const unsigned tag = (unsigned)t;
      unsigned long long vv[8];
      int guard = 0;
      for (;;) {
        bool ok = true;
        #pragma unroll
        for (int i = 0; i < 8; ++i) vv[i] = atomicOr(&src[i], 0ULL);   // RMW-read at MALL
        #pragma unroll
        for (int i = 0; i < 8; ++i) ok = ok && ((unsigned)(vv[i] >> 32) == tag);
        if (__all(ok) || ++guard >= 16384) break;
        __builtin_amdgcn_s_sleep(1);
      }
      #pragma unroll
      for (int i = 0; i < 8; ++i) {
        int k = tid * 8 + i;
        union { unsigned u; float f; } c; c.u = (unsigned)vv[i];
        h_lds[(k >> 4) * 20 + (k & 15)] = c.f;
      }
    }
    __syncthreads();
    float h[16];
    #pragma unroll
    for (int kk = 0; kk < 16; ++kk) h[kk] = h_lds[sub * 20 + kk];
    float g0i = G0[t * G4 + j];
    float g0f = G0[t * G4 + HID + j];
    float g0g = G0[t * G4 + 2 * HID + j];
    float g0o = G0[t * G4 + 3 * HID + j];
    float p0 = 0.f, p1 = 0.f, p2 = 0.f, p3 = 0.f;
    #pragma unroll
    for (int q = 0; q < 4; ++q) {
      p0 += w4[0+q].x*h[q*4+0] + w4[0+q].y*h[q*4+1] + w4[0+q].z*h[q*4+2] + w4[0+q].w*h[q*4+3];
      p1 += w4[4+q].x*h[q*4+0] + w4[4+q].y*h[q*4+1] + w4[4+q].z*h[q*4+2] + w4[4+q].w*h[q*4+3];
      p2 += w4[8+q].x*h[q*4+0] + w4[8+q].y*h[q*4+1] + w4[8+q].z*h[q*4+2] + w4[8+q].w*h[q*4+3];
      p3 += w4[12+q].x*h[q*4+0] + w4[12+q].y*h[q*4+1] + w4[12+q].z*h[q*4+2] + w4[12+q].w*h[q*4+3];
    }
    #pragma unroll
    for (int d = 1; d <= 16; d <<= 1) {       // reduce over 32 sub-lanes (stays in 32-half)
      p0 += __shfl_xor(p0, d); p1 += __shfl_xor(p1, d);
      p2 += __shfl_xor(p2, d); p3 += __shfl_xor(p3, d);
    }
    float si = fast_sigmoid(g0i + p0);
    float sf = fast_sigmoid(g0f + p1);
    float gG = fast_tanh(g0g + p2);
    float so = fast_sigmoid(g0o + p3);
    cst = sf * cst + si * gG;
    float hn = so * fast_tanh(cst);
    if (sub == 0) {
      union { float f; unsigned u; } hu; hu.f = hn;
      unsigned long long pack = ((unsigned long long)((unsigned)t + 1u) << 32) | (unsigned long long)hu.u;
      atomicExch(&hb[((t + 1) & 1) * 512 + j], pack);   // coherence-point publish
      hs[t * HID + j] = hn;
    }
  }
}

// ---------------- EWe_s / DWd_s projections (scaled by log2e) ----------------
__global__ __launch_bounds__(256) void kProj(const float* Weh, const float* beh, float* ws) {
  int bid = blockIdx.x;                 // 0..190
  bool enc = bid < K_ENC;
  int row = enc ? bid : bid - K_ENC;
  const float* in = ws + (enc ? OFF_EENC : OFF_D) + row * HID;
  __shared__ float sin_[HID];
  int tid = threadIdx.x;
  sin_[tid] = in[tid]; sin_[tid + 256] = in[tid + 256];
  __syncthreads();
  if (tid < EMB) {
    const float* wr = Weh + tid * 1024 + (enc ? 0 : HID);
    float s = 0.f;
    #pragma unroll 4
    for (int h = 0; h < HID; ++h) s += sin_[h] * wr[h];
    if (!enc) s += beh[tid];
    ws[(enc ? OFF_EWE : OFF_DWD) + row * EMB + tid] = s * LOG2E;
  }
}

// ---------------- fused logits GEMM (bf16 MFMA) + online sum(2^s) ----------------
__global__ __launch_bounds__(256) void kLogits(float* ws) {
  const int t = blockIdx.x >> 2;
  const int chunk = blockIdx.x & 3;
  const int tid = threadIdx.x;
  const int lane = tid & 63;
  const int wv = tid >> 6;
  const int quad = lane >> 4, l15 = lane & 15;
  __shared__ __align__(16) unsigned short A[64 * 128];   // hpre_s bf16, [m][k] k-padded to 128
  const float* EWe = ws + OFF_EWE;
  const float* DWd = ws + OFF_DWD + t * EMB;
  for (int idx = tid; idx < 64 * 128; idx += 256) {
    int m = idx >> 7, k = idx & 127;
    float hv = 0.f;
    if (k < EMB) { float s = EWe[m * EMB + k] + DWd[k]; hv = s > 0.f ? s : 0.f; }
    A[idx] = f2bf(hv);
  }
  __syncthreads();
  short8 af[4][4];   // A fragments persistent in VGPRs: [mtile][kblock]
  #pragma unroll
  for (int mt = 0; mt < 4; ++mt)
    #pragma unroll
    for (int kb = 0; kb < 4; ++kb)
      af[mt][kb] = *(const short8*)&A[(mt * 16 + l15) * 128 + kb * 32 + quad * 8];
  const unsigned short* wem = (const unsigned short*)(ws + OFF_WEM);
  const float* bem_s = ws + OFF_BEM;
  float rs[4][4];
  #pragma unroll
  for (int a = 0; a < 4; ++a)
    #pragma unroll
    for (int b = 0; b < 4; ++b) rs[a][b] = 0.f;
  int vt = chunk * 500 + wv;
  short8 nb0, nb1, nb2, nb3; float nbi;
  nb0 = *(const short8*)&wem[(vt * 4 + 0) * 512 + lane * 8];
  nb1 = *(const short8*)&wem[(vt * 4 + 1) * 512 + lane * 8];
  nb2 = *(const short8*)&wem[(vt * 4 + 2) * 512 + lane * 8];
  nb3 = *(const short8*)&wem[(vt * 4 + 3) * 512 + lane * 8];
  nbi = bem_s[vt * 16 + l15];
  for (int ii = wv; ii < 500; ii += 4) {
    short8 cb0 = nb0, cb1 = nb1, cb2 = nb2, cb3 = nb3;
    float cbi = nbi;
    int nvt = vt + 4;
    if (ii + 4 < 500) {   // software pipeline next B tile
      nb0 = *(const short8*)&wem[(nvt * 4 + 0) * 512 + lane * 8];
      nb1 = *(const short8*)&wem[(nvt * 4 + 1) * 512 + lane * 8];
      nb2 = *(const short8*)&wem[(nvt * 4 + 2) * 512 + lane * 8];
      nb3 = *(const short8*)&wem[(nvt * 4 + 3) * 512 + lane * 8];
      nbi = bem_s[nvt * 16 + l15];
    }
    f32x4 acc[4];
    #pragma unroll
    for (int mt = 0; mt < 4; ++mt) acc[mt] = (f32x4){cbi, cbi, cbi, cbi};  // init with bem
    #pragma unroll
    for (int mt = 0; mt < 4; ++mt) {
      acc[mt] = __builtin_amdgcn_mfma_f32_16x16x32_bf16(af[mt][0], cb0, acc[mt], 0, 0, 0);
      acc[mt] = __builtin_amdgcn_mfma_f32_16x16x32_bf16(af[mt][1], cb1, acc[mt], 0, 0, 0);
      acc[mt] = __builtin_amdgcn_mfma_f32_16x16x32_bf16(af[mt][2], cb2, acc[mt], 0, 0, 0);
      acc[mt] = __builtin_amdgcn_mfma_f32_16x16x32_bf16(af[mt][3], cb3, acc[mt], 0, 0, 0);
    }
    #pragma unroll
    for (int mt = 0; mt < 4; ++mt)
      #pragma unroll
      for (int r = 0; r < 4; ++r)
        rs[mt][r] += __builtin_amdgcn_exp2f(acc[mt][r]);   // s already includes log2e scale
    vt = nvt;
  }
  // reduce across the 16 column-lanes of each quad, then one atomic per row
  #pragma unroll
  for (int d = 1; d < 16; d <<= 1)
    #pragma unroll
    for (int mt = 0; mt < 4; ++mt)
      #pragma unroll
      for (int r = 0; r < 4; ++r)
        rs[mt][r] += __shfl_xor(rs[mt][r], d);
  if (l15 == 0) {
    float* sum = ws + OFF_SUM + t * 64;
    #pragma unroll
    for (int mt = 0; mt < 4; ++mt)
      #pragma unroll
      for (int r = 0; r < 4; ++r)
        atomicAdd(&sum[mt * 16 + quad * 4 + r], rs[mt][r]);
  }
}

// ---------------- emission = ln2 * (s_word - log2(sum 2^s)), s_word in fp32 ----------------
__global__ __launch_bounds__(256) void kEmission(const int* y, const float* Wem, float* ws) {
  int gid = blockIdx.x * 256 + threadIdx.x;
  if (gid >= 127 * 64) return;
  int t = gid >> 6, m = gid & 63;
  const float* ew = ws + OFF_EWE + m * EMB;
  const float* dw = ws + OFF_DWD + t * EMB;
  int wt = y[t + 1];
  const float* wr = Wem + wt * EMB;
  float s = ws[OFF_BEM + wt];
  #pragma unroll 4
  for (int e = 0; e < EMB; ++e) {
    float h = ew[e] + dw[e];
    h = h > 0.f ? h : 0.f;
    s += h * wr[e];
  }
  ws[OFF_EM + gid] = LN2 * (s - __builtin_amdgcn_logf(ws[OFF_SUM + gid]));
}

// ---------------- Viterbi: prefix-max trick + backtrace ----------------
// tranm[i][j] = fe + fs*(63-i-j) (i+j<64). scores[i][j] = q[i] + fe + fs*(63-j), q[i]=pa[i]-fs*i.
// flip cancels: new_pa[j] = P[j] + fe + fs*j + em[t][j]; ind'[j] = argP[j]  (P = prefix max of q).
__global__ __launch_bounds__(256) void kViterbi(const float* ws, float* out) {
  __shared__ float em_lds[127 * 64];
  __shared__ int   inds[128 * 64];
  __shared__ float sval;
  const int tid = threadIdx.x;
  for (int i = tid; i < 127 * 64; i += 256) em_lds[i] = ws[OFF_EM + i];
  if (tid < 64) inds[tid] = 0;   // indices row 0
  __syncthreads();
  if (tid < 64) {
    const int j = tid;
    const float fs = -0.4054651081081644f;   // log(128/192)
    const float fe = -1.0986122886681098f;   // log(64/192)
    float pa = 0.f;
    float emnext = em_lds[j];
    for (int t = 0; t < 127; ++t) {
      float emc = emnext;
      if (t < 126) emnext = em_lds[(t + 1) * 64 + j];
      float v = fmaf(-fs, (float)j, pa);   // q[j]
      int idx = j;
      #pragma unroll
      for (int d = 1; d < 64; d <<= 1) {   // inclusive prefix max, earliest argmax on ties
        float vv = __shfl_up(v, d);
        int   ii = __shfl_up(idx, d);
        bool cur = v > vv;                 // strict >: keep earlier index on ties
        v   = cur ? v : vv;
        idx = cur ? idx : ii;
      }
      pa = v + fe + fs * (float)j + emc;
      inds[(t + 1) * 64 + j] = idx;
    }
    if (j == 63) sval = pa;
  }
  __syncthreads();
  if (tid == 0) {
    int ind = 63;
    for (int t = 127; t >= 0; --t) {
      ind = inds[t * 64 + ind];
      out[t] = (float)ind;
    }
    out[128] = sval;
  }
}

extern "C" void kernel_launch(void* const* d_in, const int* in_sizes, int n_in,
                              void* d_out, int out_size, void* d_ws, size_t ws_size,
                              hipStream_t stream) {
  const int*   x    = (const int*)d_in[0];
  const int*   y    = (const int*)d_in[1];
  const float* emb  = (const float*)d_in[2];
  const float* eWih = (const float*)d_in[3];
  const float* eWhh = (const float*)d_in[4];
  const float* ebih = (const float*)d_in[5];
  const float* ebhh = (const float*)d_in[6];
  const float* dWih = (const float*)d_in[7];
  const float* dWhh = (const float*)d_in[8];
  const float* dbih = (const float*)d_in[9];
  const float* dbhh = (const float*)d_in[10];
  const float* Weh  = (const float*)d_in[11];
  const float* beh  = (const float*)d_in[12];
  const float* Wem  = (const float*)d_in[13];
  const float* bem  = (const float*)d_in[14];
  float* ws  = (float*)d_ws;
  float* out = (float*)d_out;

  hipLaunchKernelGGL(kZero,     dim3(49),    dim3(256), 0, stream, ws);
  hipLaunchKernelGGL(kG0,       dim3(1528),  dim3(256), 0, stream, x, y, emb, eWih, ebih, ebhh, dWih, dbih, dbhh, ws);
  hipLaunchKernelGGL(kWemPrep,  dim3(16000), dim3(256), 0, stream, Wem, bem, ws);
  hipLaunchKernelGGL(kLstm,     dim3(64),    dim3(512), 0, stream, eWhh, dWhh, ws);
  hipLaunchKernelGGL(kProj,     dim3(191),   dim3(256), 0, stream, Weh, beh, ws);
  hipLaunchKernelGGL(kLogits,   dim3(508),   dim3(256), 0, stream, ws);
  hipLaunchKernelGGL(kEmission, dim3(32),    dim3(256), 0, stream, y, Wem, ws);
  hipLaunchKernelGGL(kViterbi,  dim3(1),     dim3(256), 0, stream, ws, out);
}

// Round 6
// 664.346 us; speedup vs baseline: 10651.4847x; 1.0057x over previous
//
#include <hip/hip_runtime.h>

// Seq2SeqWithAlignment: enc/dec LSTM -> hpre -> logits logsumexp -> Viterbi align.
// K=64 enc steps, T=128 dec tokens (127 dec steps used), H=512, E=100, V=32000.

#define K_ENC 64
#define HID   512
#define EMB   100
#define VOC   32000
#define G4    2048   // 4*HID

typedef __attribute__((ext_vector_type(8))) short  short8;
typedef __attribute__((ext_vector_type(4))) float  f32x4;

#define LOG2E 1.4426950408889634f
#define LN2   0.6931471805599453f

__device__ __forceinline__ unsigned short f2bf(float f) {
  union { float f; unsigned u; } x; x.f = f;
  unsigned r = x.u + 0x7FFFu + ((x.u >> 16) & 1u);  // RNE
  return (unsigned short)(r >> 16);
}

__device__ __forceinline__ float fast_sigmoid(float x) {
  return __builtin_amdgcn_rcpf(1.f + __builtin_amdgcn_exp2f(-LOG2E * x));
}
__device__ __forceinline__ float fast_tanh(float x) {
  return 1.f - 2.f * __builtin_amdgcn_rcpf(1.f + __builtin_amdgcn_exp2f(2.f * LOG2E * x));
}

// ---------------- workspace layout (float offsets) ----------------
#define OFF_PAD   0         // 256 floats: unused
#define OFF_HBUF  256       // 4096 floats = 2048 u64: tagged h channels [grp][slot][512]
#define OFF_G0E   4352      // 64*2048  : enc Wih@x + bih + bhh
#define OFF_G0D   135424    // 127*2048 : dec
#define OFF_EENC  395520    // 64*512
#define OFF_D     428288    // 127*512
#define OFF_EWE   493312    // 64*100   : log2e * Eenc@We_E^T
#define OFF_DWD   499712    // 127*100  : log2e * (D@We_D^T + beh)
#define OFF_BEM   512412    // 32000    : log2e * bem
#define OFF_SUM   544412    // 127*64   : sum of 2^s over v (atomic)
#define OFF_EM    552540    // 127*64   : emission
#define OFF_WEM   560668    // ushort[4096000]: Wem bf16 in MFMA-B fragment-linear layout
// total ~10.4 MB

// ---------------- zero init (tagged h channels => tag 0 / value 0, sumexp) ----------------
__global__ void kZero(float* ws) {
  int gid = blockIdx.x * 256 + threadIdx.x;
  if (gid < 4352) ws[gid] = 0.f;
  else if (gid < 4352 + 127 * 64) ws[OFF_SUM + gid - 4352] = 0.f;
}

// ---------------- G0 = Wih @ emb[tok] + bih + bhh ----------------
__global__ __launch_bounds__(256) void kG0(const int* x, const int* y, const float* emb,
                    const float* eWih, const float* ebih, const float* ebhh,
                    const float* dWih, const float* dbih, const float* dbhh,
                    float* ws) {
  int gid = blockIdx.x * 256 + threadIdx.x;
  const int enc_total = K_ENC * G4;
  if (gid >= enc_total + 127 * G4) return;
  bool enc = gid < enc_total;
  int loc = enc ? gid : gid - enc_total;
  int t = loc >> 11, r = loc & (G4 - 1);
  int tok = enc ? x[t] : y[t];
  const float* Wr = (enc ? eWih : dWih) + r * EMB;
  const float* er = emb + tok * EMB;
  float s = 0.f;
  #pragma unroll 4
  for (int e = 0; e < EMB; ++e) s += er[e] * Wr[e];
  s += enc ? (ebih[r] + ebhh[r]) : (dbih[r] + dbhh[r]);
  ws[(enc ? OFF_G0E : OFF_G0D) + t * G4 + r] = s;
}

// ---------------- Wem -> bf16 MFMA-B fragment-linear layout, bem scaled ----------------
// block (vt,kb) = 1KB: lane L holds Wem[vt*16+(L&15)][kb*32+(L>>4)*8+j], j=0..7 (0-pad k>=100)
__global__ __launch_bounds__(256) void kWemPrep(const float* Wem, const float* bem, float* ws) {
  int gid = blockIdx.x * 256 + threadIdx.x;   // < 4096000
  int vt = gid >> 11;
  int kb = (gid >> 9) & 3;
  int L  = (gid >> 3) & 63;
  int j  = gid & 7;
  int v = vt * 16 + (L & 15);
  int k = kb * 32 + ((L >> 4) << 3) + j;
  float val = (k < EMB) ? Wem[v * EMB + k] : 0.f;
  ((unsigned short*)(ws + OFF_WEM))[gid] = f2bf(val);
  if (gid < VOC) ws[OFF_BEM + gid] = bem[gid] * LOG2E;
}

// ---------------- persistent LSTM: 64 WGs (32 enc + 32 dec), weights in VGPRs ----------------
// Sync via tagged 64-bit words (tag<<32 | f32bits) moved with atomic RMWs ONLY:
//   producer: atomicExch (coherence point -> promptly visible to all XCDs)
//   consumer: wave 0 polls with atomicOr(ptr,0), s_sleep backoff, deposits h into LDS;
//             one __syncthreads; all 8 waves read from LDS.
// R4 lesson: relaxed agent-scope load/store polled stale per-XCD L2 lines -> 37ms/step.
// R5 lesson: VGPR_Count=48 -> weight slice NOT resident; default launch_bounds targets
//   high occupancy. 64 WGs on 256 CUs = 1 WG/CU = 2 waves/SIMD -> 256 VGPR budget legal.
//   __launch_bounds__(512, 2) declares exactly that (min 2 waves/EU -> cap 256 VGPRs).
// Poll is BOUNDED: sync failure => finite wrong answer, not a harness-timeout hang.
__global__ __launch_bounds__(512, 2) void kLstm(const float* eWhh, const float* dWhh, float* ws) {
  const int grp = blockIdx.x >> 5;            // 0=enc, 1=dec
  const int wg  = blockIdx.x & 31;
  const float* Whh = grp ? dWhh : eWhh;
  const float* G0  = ws + (grp ? OFF_G0D : OFF_G0E);
  float* hs = ws + (grp ? OFF_D : OFF_EENC);
  unsigned long long* hb = (unsigned long long*)(ws + OFF_HBUF) + grp * 1024;  // [2][512]
  const int steps = grp ? 127 : K_ENC;
  const int tid = threadIdx.x;
  const int jl = tid >> 5, sub = tid & 31;
  const int j = wg * 16 + jl;                 // owned h index
  __shared__ float h_lds[32 * 20];            // [sub][16] padded to 20 (bank spread)
  // per-thread weight slice: 4 gates x 16 k  (rows g*512+j, cols sub*16..+16) = 64 VGPRs
  float4 w4[16];
  #pragma unroll
  for (int g = 0; g < 4; ++g)
    #pragma unroll
    for (int q = 0; q < 4; ++q)
      w4[g * 4 + q] = *(const float4*)&Whh[(g * HID + j) * HID + sub * 16 + q * 4];
  float cst = 0.f;
  for (int t = 0; t < steps; ++t) {
    // ---- wave 0: coherence-point poll of all 512 words (8 per lane) ----
    if (tid < 64) {
      unsigned long long* src = hb + (t & 1) * 512 + tid * 8;
      const unsigned tag = (unsigned)t;
      unsigned long long vv[8];
      int guard = 0;
      for (;;) {
        bool ok = true;
        #pragma unroll
        for (int i = 0; i < 8; ++i) vv[i] = atomicOr(&src[i], 0ULL);   // RMW-read at MALL
        #pragma unroll
        for (int i = 0; i < 8; ++i) ok = ok && ((unsigned)(vv[i] >> 32) == tag);
        if (__all(ok) || ++guard >= 16384) break;
        __builtin_amdgcn_s_sleep(1);
      }
      #pragma unroll
      for (int i = 0; i < 8; ++i) {
        int k = tid * 8 + i;
        union { unsigned u; float f; } c; c.u = (unsigned)vv[i];
        h_lds[(k >> 4) * 20 + (k & 15)] = c.f;
      }
    }
    __syncthreads();
    float h[16];
    #pragma unroll
    for (int kk = 0; kk < 16; ++kk) h[kk] = h_lds[sub * 20 + kk];
    float g0i = G0[t * G4 + j];
    float g0f = G0[t * G4 + HID + j];
    float g0g = G0[t * G4 + 2 * HID + j];
    float g0o = G0[t * G4 + 3 * HID + j];
    float p0 = 0.f, p1 = 0.f, p2 = 0.f, p3 = 0.f;
    #pragma unroll
    for (int q = 0; q < 4; ++q) {
      p0 += w4[0+q].x*h[q*4+0] + w4[0+q].y*h[q*4+1] + w4[0+q].z*h[q*4+2] + w4[0+q].w*h[q*4+3];
      p1 += w4[4+q].x*h[q*4+0] + w4[4+q].y*h[q*4+1] + w4[4+q].z*h[q*4+2] + w4[4+q].w*h[q*4+3];
      p2 += w4[8+q].x*h[q*4+0] + w4[8+q].y*h[q*4+1] + w4[8+q].z*h[q*4+2] + w4[8+q].w*h[q*4+3];
      p3 += w4[12+q].x*h[q*4+0] + w4[12+q].y*h[q*4+1] + w4[12+q].z*h[q*4+2] + w4[12+q].w*h[q*4+3];
    }
    #pragma unroll
    for (int d = 1; d <= 16; d <<= 1) {       // reduce over 32 sub-lanes (stays in 32-half)
      p0 += __shfl_xor(p0, d); p1 += __shfl_xor(p1, d);
      p2 += __shfl_xor(p2, d); p3 += __shfl_xor(p3, d);
    }
    float si = fast_sigmoid(g0i + p0);
    float sf = fast_sigmoid(g0f + p1);
    float gG = fast_tanh(g0g + p2);
    float so = fast_sigmoid(g0o + p3);
    cst = sf * cst + si * gG;
    float hn = so * fast_tanh(cst);
    if (sub == 0) {
      union { float f; unsigned u; } hu; hu.f = hn;
      unsigned long long pack = ((unsigned long long)((unsigned)t + 1u) << 32) | (unsigned long long)hu.u;
      atomicExch(&hb[((t + 1) & 1) * 512 + j], pack);   // coherence-point publish
      hs[t * HID + j] = hn;
    }
  }
}

// ---------------- EWe_s / DWd_s projections (scaled by log2e) ----------------
__global__ __launch_bounds__(256) void kProj(const float* Weh, const float* beh, float* ws) {
  int bid = blockIdx.x;                 // 0..190
  bool enc = bid < K_ENC;
  int row = enc ? bid : bid - K_ENC;
  const float* in = ws + (enc ? OFF_EENC : OFF_D) + row * HID;
  __shared__ float sin_[HID];
  int tid = threadIdx.x;
  sin_[tid] = in[tid]; sin_[tid + 256] = in[tid + 256];
  __syncthreads();
  if (tid < EMB) {
    const float* wr = Weh + tid * 1024 + (enc ? 0 : HID);
    float s = 0.f;
    #pragma unroll 4
    for (int h = 0; h < HID; ++h) s += sin_[h] * wr[h];
    if (!enc) s += beh[tid];
    ws[(enc ? OFF_EWE : OFF_DWD) + row * EMB + tid] = s * LOG2E;
  }
}

// ---------------- fused logits GEMM (bf16 MFMA) + online sum(2^s) ----------------
__global__ __launch_bounds__(256) void kLogits(float* ws) {
  const int t = blockIdx.x >> 2;
  const int chunk = blockIdx.x & 3;
  const int tid = threadIdx.x;
  const int lane = tid & 63;
  const int wv = tid >> 6;
  const int quad = lane >> 4, l15 = lane & 15;
  __shared__ __align__(16) unsigned short A[64 * 128];   // hpre_s bf16, [m][k] k-padded to 128
  const float* EWe = ws + OFF_EWE;
  const float* DWd = ws + OFF_DWD + t * EMB;
  for (int idx = tid; idx < 64 * 128; idx += 256) {
    int m = idx >> 7, k = idx & 127;
    float hv = 0.f;
    if (k < EMB) { float s = EWe[m * EMB + k] + DWd[k]; hv = s > 0.f ? s : 0.f; }
    A[idx] = f2bf(hv);
  }
  __syncthreads();
  short8 af[4][4];   // A fragments persistent in VGPRs: [mtile][kblock]
  #pragma unroll
  for (int mt = 0; mt < 4; ++mt)
    #pragma unroll
    for (int kb = 0; kb < 4; ++kb)
      af[mt][kb] = *(const short8*)&A[(mt * 16 + l15) * 128 + kb * 32 + quad * 8];
  const unsigned short* wem = (const unsigned short*)(ws + OFF_WEM);
  const float* bem_s = ws + OFF_BEM;
  float rs[4][4];
  #pragma unroll
  for (int a = 0; a < 4; ++a)
    #pragma unroll
    for (int b = 0; b < 4; ++b) rs[a][b] = 0.f;
  int vt = chunk * 500 + wv;
  short8 nb0, nb1, nb2, nb3; float nbi;
  nb0 = *(const short8*)&wem[(vt * 4 + 0) * 512 + lane * 8];
  nb1 = *(const short8*)&wem[(vt * 4 + 1) * 512 + lane * 8];
  nb2 = *(const short8*)&wem[(vt * 4 + 2) * 512 + lane * 8];
  nb3 = *(const short8*)&wem[(vt * 4 + 3) * 512 + lane * 8];
  nbi = bem_s[vt * 16 + l15];
  for (int ii = wv; ii < 500; ii += 4) {
    short8 cb0 = nb0, cb1 = nb1, cb2 = nb2, cb3 = nb3;
    float cbi = nbi;
    int nvt = vt + 4;
    if (ii + 4 < 500) {   // software pipeline next B tile
      nb0 = *(const short8*)&wem[(nvt * 4 + 0) * 512 + lane * 8];
      nb1 = *(const short8*)&wem[(nvt * 4 + 1) * 512 + lane * 8];
      nb2 = *(const short8*)&wem[(nvt * 4 + 2) * 512 + lane * 8];
      nb3 = *(const short8*)&wem[(nvt * 4 + 3) * 512 + lane * 8];
      nbi = bem_s[nvt * 16 + l15];
    }
    f32x4 acc[4];
    #pragma unroll
    for (int mt = 0; mt < 4; ++mt) acc[mt] = (f32x4){cbi, cbi, cbi, cbi};  // init with bem
    #pragma unroll
    for (int mt = 0; mt < 4; ++mt) {
      acc[mt] = __builtin_amdgcn_mfma_f32_16x16x32_bf16(af[mt][0], cb0, acc[mt], 0, 0, 0);
      acc[mt] = __builtin_amdgcn_mfma_f32_16x16x32_bf16(af[mt][1], cb1, acc[mt], 0, 0, 0);
      acc[mt] = __builtin_amdgcn_mfma_f32_16x16x32_bf16(af[mt][2], cb2, acc[mt], 0, 0, 0);
      acc[mt] = __builtin_amdgcn_mfma_f32_16x16x32_bf16(af[mt][3], cb3, acc[mt], 0, 0, 0);
    }
    #pragma unroll
    for (int mt = 0; mt < 4; ++mt)
      #pragma unroll
      for (int r = 0; r < 4; ++r)
        rs[mt][r] += __builtin_amdgcn_exp2f(acc[mt][r]);   // s already includes log2e scale
    vt = nvt;
  }
  // reduce across the 16 column-lanes of each quad, then one atomic per row
  #pragma unroll
  for (int d = 1; d < 16; d <<= 1)
    #pragma unroll
    for (int mt = 0; mt < 4; ++mt)
      #pragma unroll
      for (int r = 0; r < 4; ++r)
        rs[mt][r] += __shfl_xor(rs[mt][r], d);
  if (l15 == 0) {
    float* sum = ws + OFF_SUM + t * 64;
    #pragma unroll
    for (int mt = 0; mt < 4; ++mt)
      #pragma unroll
      for (int r = 0; r < 4; ++r)
        atomicAdd(&sum[mt * 16 + quad * 4 + r], rs[mt][r]);
  }
}

// ---------------- emission = ln2 * (s_word - log2(sum 2^s)), s_word in fp32 ----------------
__global__ __launch_bounds__(256) void kEmission(const int* y, const float* Wem, float* ws) {
  int gid = blockIdx.x * 256 + threadIdx.x;
  if (gid >= 127 * 64) return;
  int t = gid >> 6, m = gid & 63;
  const float* ew = ws + OFF_EWE + m * EMB;
  const float* dw = ws + OFF_DWD + t * EMB;
  int wt = y[t + 1];
  const float* wr = Wem + wt * EMB;
  float s = ws[OFF_BEM + wt];
  #pragma unroll 4
  for (int e = 0; e < EMB; ++e) {
    float h = ew[e] + dw[e];
    h = h > 0.f ? h : 0.f;
    s += h * wr[e];
  }
  ws[OFF_EM + gid] = LN2 * (s - __builtin_amdgcn_logf(ws[OFF_SUM + gid]));
}

// ---------------- Viterbi: prefix-max trick + backtrace ----------------
// tranm[i][j] = fe + fs*(63-i-j) (i+j<64). scores[i][j] = q[i] + fe + fs*(63-j), q[i]=pa[i]-fs*i.
// flip cancels: new_pa[j] = P[j] + fe + fs*j + em[t][j]; ind'[j] = argP[j]  (P = prefix max of q).
__global__ __launch_bounds__(256) void kViterbi(const float* ws, float* out) {
  __shared__ float em_lds[127 * 64];
  __shared__ int   inds[128 * 64];
  __shared__ float sval;
  const int tid = threadIdx.x;
  for (int i = tid; i < 127 * 64; i += 256) em_lds[i] = ws[OFF_EM + i];
  if (tid < 64) inds[tid] = 0;   // indices row 0
  __syncthreads();
  if (tid < 64) {
    const int j = tid;
    const float fs = -0.4054651081081644f;   // log(128/192)
    const float fe = -1.0986122886681098f;   // log(64/192)
    float pa = 0.f;
    float emnext = em_lds[j];
    for (int t = 0; t < 127; ++t) {
      float emc = emnext;
      if (t < 126) emnext = em_lds[(t + 1) * 64 + j];
      float v = fmaf(-fs, (float)j, pa);   // q[j]
      int idx = j;
      #pragma unroll
      for (int d = 1; d < 64; d <<= 1) {   // inclusive prefix max, earliest argmax on ties
        float vv = __shfl_up(v, d);
        int   ii = __shfl_up(idx, d);
        bool cur = v > vv;                 // strict >: keep earlier index on ties
        v   = cur ? v : vv;
        idx = cur ? idx : ii;
      }
      pa = v + fe + fs * (float)j + emc;
      inds[(t + 1) * 64 + j] = idx;
    }
    if (j == 63) sval = pa;
  }
  __syncthreads();
  if (tid == 0) {
    int ind = 63;
    for (int t = 127; t >= 0; --t) {
      ind = inds[t * 64 + ind];
      out[t] = (float)ind;
    }
    out[128] = sval;
  }
}

extern "C" void kernel_launch(void* const* d_in, const int* in_sizes, int n_in,
                              void* d_out, int out_size, void* d_ws, size_t ws_size,
                              hipStream_t stream) {
  const int*   x    = (const int*)d_in[0];
  const int*   y    = (const int*)d_in[1];
  const float* emb  = (const float*)d_in[2];
  const float* eWih = (const float*)d_in[3];
  const float* eWhh = (const float*)d_in[4];
  const float* ebih = (const float*)d_in[5];
  const float* ebhh = (const float*)d_in[6];
  const float* dWih = (const float*)d_in[7];
  const float* dWhh = (const float*)d_in[8];
  const float* dbih = (const float*)d_in[9];
  const float* dbhh = (const float*)d_in[10];
  const float* Weh  = (const float*)d_in[11];
  const float* beh  = (const float*)d_in[12];
  const float* Wem  = (const float*)d_in[13];
  const float* bem  = (const float*)d_in[14];
  float* ws  = (float*)d_ws;
  float* out = (float*)d_out;

  hipLaunchKernelGGL(kZero,     dim3(49),    dim3(256), 0, stream, ws);
  hipLaunchKernelGGL(kG0,       dim3(1528),  dim3(256), 0, stream, x, y, emb, eWih, ebih, ebhh, dWih, dbih, dbhh, ws);
  hipLaunchKernelGGL(kWemPrep,  dim3(16000), dim3(256), 0, stream, Wem, bem, ws);
  hipLaunchKernelGGL(kLstm,     dim3(64),    dim3(512), 0, stream, eWhh, dWhh, ws);
  hipLaunchKernelGGL(kProj,     dim3(191),   dim3(256), 0, stream, Weh, beh, ws);
  hipLaunchKernelGGL(kLogits,   dim3(508),   dim3(256), 0, stream, ws);
  hipLaunchKernelGGL(kEmission, dim3(32),    dim3(256), 0, stream, y, Wem, ws);
  hipLaunchKernelGGL(kViterbi,  dim3(1),     dim3(256), 0, stream, ws, out);
}